// Round 8
// baseline (434.349 us; speedup 1.0000x reference)
//
#include <hip/hip_runtime.h>
#include <math.h>

#define KCODES 1024
#define DIM 64
#define NTOT 131072          // 32*64*64 rows
#define QELEMS 8388608       // 32*64*64*64
#define TAU 1e-3f            // contested-margin threshold (>> approx error bound)
#define WCAP 65536           // worklist capacity (aliases dwacc region)

typedef _Float16 half8 __attribute__((ext_vector_type(8)));
typedef float floatx4 __attribute__((ext_vector_type(4)));

// ws layout (4B units):
//   0      counts_i [1024] int     (zeroed)
//   1024   scal [3]: sumsq,nsum,ent; [1027] wcount int (zeroed)
//   1028   cursor [1024] int       (zeroed)
//   2052   dwacc [65536] float     (zeroed; doubles as refine worklist, re-zeroed)
//   67588  enorm [1024] float
//   68612  epk [98304 floats = 196608 halves]  (argmin phase)
//   68612  keys [131072] int                    (tail phase, aliases epk)
//   199684 flat_x [8388608] float  (optional)
#define WS_ZERO_FLOATS 67588
#define WS_FLAT_OFF 199684
#define WS_NEED_FLAT ((size_t)(WS_FLAT_OFF + QELEMS) * 4)

__global__ __launch_bounds__(256) void vq_enorm_kernel(const float* __restrict__ embed,
                                                       float* __restrict__ enorm) {
    int k = blockIdx.x * 256 + threadIdx.x;
    if (k < KCODES) {
        const float4* e4 = (const float4*)(embed + (k << 6));
        float s = 0.f;
#pragma unroll
        for (int j = 0; j < 16; ++j) {
            float4 v = e4[j];
            s += v.x * v.x + v.y * v.y + v.z * v.z + v.w * v.w;
        }
        enorm[k] = s;
    }
}

// Pack embed into MFMA A-fragment layout, fp16 3-term split, K=192.
__global__ __launch_bounds__(256) void vq_epack_kernel(const float* __restrict__ embed,
                                                       _Float16* __restrict__ epk) {
    int tg   = blockIdx.x * 256 + threadIdx.x;   // 0..4095
    int ctg  = tg >> 6;
    int lane = tg & 63;
    int c    = ctg * 16 + (lane & 15);
    int q    = lane >> 4;
    const float* er = embed + c * 64;
    float4 f0 = *(const float4*)(er + q * 8);
    float4 f1 = *(const float4*)(er + q * 8 + 4);
    float4 g0 = *(const float4*)(er + 32 + q * 8);
    float4 g1 = *(const float4*)(er + 32 + q * 8 + 4);
    float va[8] = {f0.x, f0.y, f0.z, f0.w, f1.x, f1.y, f1.z, f1.w};
    float vb[8] = {g0.x, g0.y, g0.z, g0.w, g1.x, g1.y, g1.z, g1.w};
    half8 h0, h1, l0, l1;
#pragma unroll
    for (int j = 0; j < 8; ++j) {
        _Float16 ah = (_Float16)va[j];
        _Float16 bh = (_Float16)vb[j];
        h0[j] = ah;
        h1[j] = bh;
        l0[j] = (_Float16)(va[j] - (float)ah);
        l1[j] = (_Float16)(vb[j] - (float)bh);
    }
    half8* o = (half8*)epk;
    int base = ctg * 6 * 64 + lane;
    o[base]           = h0;
    o[base + 64]      = h1;
    o[base + 128]     = h0;
    o[base + 192]     = h1;
    o[base + 256]     = l0;
    o[base + 320]     = l1;
}

// MFMA argmin with top-2 margin tracking + contested worklist.
__global__ __launch_bounds__(256, 2) void vq_argmin_mfma(
    const float* __restrict__ in,        // [32][64][64][64] NCHW
    const float* __restrict__ embed,
    const float* __restrict__ enorm,
    const _Float16* __restrict__ epk,
    float* __restrict__ out_quant,
    float* __restrict__ out_idx,
    int*   __restrict__ counts_i,
    float* __restrict__ sumsq,
    float* __restrict__ flat_x,          // or nullptr
    int*   __restrict__ wlist,           // [WCAP] (dwacc region, zeroed)
    int*   __restrict__ wcount)          // zeroed
{
    __shared__ __align__(16) char smem_raw[60928];
    half8* xsf = (half8*)smem_raw;                 // [8pt][6kc][64lane] = 49152 B
    float* en  = (float*)(smem_raw + 49152);       // 1024 f (reused as hist)
    float* wredv  = (float*)(smem_raw + 53248);    // [4][128]
    int*   wredi  = (int*)(smem_raw + 55296);      // [4][128]
    float* wred2  = (float*)(smem_raw + 57344);    // [4][128]
    int*   idxs_s = (int*)(smem_raw + 59392);      // [128]
    float* rsum   = (float*)(smem_raw + 59904);    // [256]

    const int t    = threadIdx.x;
    const int blk  = blockIdx.x;                   // 0..1023
    const int b    = blk >> 5;
    const int h0   = (blk & 31) << 1;
    const int lane = t & 63;
    const int w    = t >> 6;
    const int q    = lane >> 4;
    const float* xb = in + b * 262144 + h0 * 64;

    for (int i = t; i < KCODES; i += 256) en[i] = enorm[i];

    // stage x: fp32 read, fp16 split, B-frag LDS layout, flat dump
    {
        const int p  = t & 127;
        const int dg = t >> 7;
        float v[32];
#pragma unroll
        for (int m = 0; m < 32; ++m) v[m] = xb[(dg * 32 + m) * 4096 + p];
        if (flat_x) {
            float* dst = flat_x + ((size_t)(blk * 128 + p) << 6) + dg * 32;
#pragma unroll
            for (int m4 = 0; m4 < 8; ++m4) {
                float4 fv = {v[m4 * 4], v[m4 * 4 + 1], v[m4 * 4 + 2], v[m4 * 4 + 3]};
                *(float4*)(dst + m4 * 4) = fv;
            }
        }
        const int pt = p >> 4;
        const int pl = p & 15;
#pragma unroll
        for (int bi = 0; bi < 4; ++bi) {
            half8 hv, lv;
#pragma unroll
            for (int j = 0; j < 8; ++j) {
                float x = v[bi * 8 + j];
                _Float16 xh = (_Float16)x;
                hv[j] = xh;
                lv[j] = (_Float16)(x - (float)xh);
            }
            int lt = bi * 16 + pl;
            xsf[(pt * 6 + dg) * 64 + lt]       = hv;
            xsf[(pt * 6 + 2 + dg) * 64 + lt]   = lv;
            xsf[(pt * 6 + 4 + dg) * 64 + lt]   = hv;
        }
    }
    __syncthreads();

    float v1[8], v2[8];
    int   i1[8];
#pragma unroll
    for (int i = 0; i < 8; ++i) { v1[i] = 3.4e38f; v2[i] = 3.4e38f; i1[i] = 0; }

    const half8* epk8 = (const half8*)epk;
    for (int rr = 0; rr < 4; ++rr) {
        half8 a[4][6];
        floatx4 enf[4];
#pragma unroll
        for (int ct = 0; ct < 4; ++ct) {
            int ctg = w * 16 + rr * 4 + ct;
#pragma unroll
            for (int kc = 0; kc < 6; ++kc)
                a[ct][kc] = epk8[(ctg * 6 + kc) * 64 + lane];
            enf[ct] = *(const floatx4*)&en[ctg * 16 + q * 4];
        }
#pragma unroll
        for (int pt = 0; pt < 8; ++pt) {
            half8 bf[6];
#pragma unroll
            for (int kc = 0; kc < 6; ++kc)
                bf[kc] = xsf[(pt * 6 + kc) * 64 + lane];
            floatx4 acc[4];
#pragma unroll
            for (int ct = 0; ct < 4; ++ct) {
                floatx4 z = {0.f, 0.f, 0.f, 0.f};
                acc[ct] = z;
            }
#pragma unroll
            for (int kc = 0; kc < 6; ++kc)
#pragma unroll
                for (int ct = 0; ct < 4; ++ct)
                    acc[ct] = __builtin_amdgcn_mfma_f32_16x16x32_f16(
                        a[ct][kc], bf[kc], acc[ct], 0, 0, 0);
#pragma unroll
            for (int ct = 0; ct < 4; ++ct) {
                int c0 = (w * 16 + rr * 4 + ct) * 16 + q * 4;
#pragma unroll
                for (int r = 0; r < 4; ++r) {
                    float dv = enf[ct][r] - 2.0f * acc[ct][r];
                    if (dv < v1[pt]) { v2[pt] = v1[pt]; v1[pt] = dv; i1[pt] = c0 + r; }
                    else if (dv < v2[pt]) v2[pt] = dv;
                }
            }
        }
    }
    __syncthreads();

    int* hist = (int*)en;
    for (int i = t; i < KCODES; i += 256) hist[i] = 0;
#pragma unroll
    for (int pt = 0; pt < 8; ++pt) {
        float a1 = v1[pt], a2 = v2[pt];
        int   ai = i1[pt];
#pragma unroll
        for (int off = 16; off <= 32; off <<= 1) {
            float o1 = __shfl_xor(a1, off, 64);
            int   oi = __shfl_xor(ai, off, 64);
            float o2 = __shfl_xor(a2, off, 64);
            if (o1 < a1 || (o1 == a1 && oi < ai)) {
                a2 = fminf(a1, o2); a1 = o1; ai = oi;
            } else {
                a2 = fminf(a2, o1);
            }
        }
        if (lane < 16) {
            int p = pt * 16 + lane;
            wredv[w * 128 + p] = a1;
            wredi[w * 128 + p] = ai;
            wred2[w * 128 + p] = a2;
        }
    }
    __syncthreads();
    if (t < 128) {
        float b1 = wredv[t], b2 = wred2[t];
        int   bi = wredi[t];
#pragma unroll
        for (int g = 1; g < 4; ++g) {
            float o1 = wredv[g * 128 + t];
            int   oi = wredi[g * 128 + t];
            float o2 = wred2[g * 128 + t];
            if (o1 < b1 || (o1 == b1 && oi < bi)) {
                b2 = fminf(b1, o2); b1 = o1; bi = oi;
            } else {
                b2 = fminf(b2, o1);
            }
        }
        idxs_s[t] = bi;
        out_idx[(blk << 7) + t] = (float)bi;
        atomicAdd(&hist[bi], 1);
        if (b2 - b1 < TAU) {
            int pos = atomicAdd(wcount, 1);
            if (pos < WCAP) wlist[pos] = (blk << 7) + t;
        }
    }
    __syncthreads();
    for (int i = t; i < KCODES; i += 256) {
        int v = hist[i];
        if (v) atomicAdd(&counts_i[i], v);
    }

    // quant write + sumsq (x reconstructed from fp16 split in LDS)
    {
        const int hw = t & 127;
        const int dh = t >> 7;
        const int k  = idxs_s[hw];
        const float* eq = embed + (k << 6);
        float* ob = out_quant + b * 262144 + h0 * 64 + hw;
        const int pt = hw >> 4, pl = hw & 15;
        const _Float16* xsh = (const _Float16*)smem_raw;
        float ls = 0.f;
#pragma unroll
        for (int m = 0; m < 32; ++m) {
            int d  = dh * 32 + m;
            int lq = m >> 3;
            int j  = m & 7;
            int ih = ((pt * 6 + dh) * 64 + lq * 16 + pl) * 8 + j;
            int il = ((pt * 6 + 2 + dh) * 64 + lq * 16 + pl) * 8 + j;
            float x = (float)xsh[ih] + (float)xsh[il];
            float qv = eq[d];
            ob[d * 4096] = qv;
            float e = qv - x;
            ls += e * e;
        }
        rsum[t] = ls;
    }
    __syncthreads();
    for (int s = 128; s > 0; s >>= 1) {
        if (t < s) rsum[t] += rsum[t + s];
        __syncthreads();
    }
    if (t == 0) atomicAdd(sumsq, rsum[0]);
}

// Exact double-precision refine of contested pixels; patches idx/counts/quant/sumsq.
// One wave per worklist entry (grid-stride). Re-zeroes consumed wlist entries
// (wlist aliases dwacc, which must be zero before vq_dw_kernel).
__global__ __launch_bounds__(256) void vq_refine_kernel(
    const float* __restrict__ embed,
    const float* __restrict__ in,
    const float* __restrict__ flat_x,    // may be null
    float* __restrict__ out_idx,
    float* __restrict__ out_quant,
    int*   __restrict__ counts_i,
    float* __restrict__ scal,            // [0]=sumsq
    int*   __restrict__ wlist,
    const int* __restrict__ wcount)
{
    const int lane = threadIdx.x & 63;
    const int gw   = (blockIdx.x << 2) + (threadIdx.x >> 6);
    const int nw   = gridDim.x << 2;
    int count = *wcount;
    if (count > WCAP) count = WCAP;

    for (int e = gw; e < count; e += nw) {
        int r = wlist[e];
        int b = r >> 12, rem = r & 4095;
        float4 xr[16];
        if (flat_x) {
            const float4* xs4 = (const float4*)(flat_x + ((size_t)r << 6));
#pragma unroll
            for (int qq = 0; qq < 16; ++qq) xr[qq] = xs4[qq];
        } else {
#pragma unroll
            for (int qq = 0; qq < 16; ++qq) {
                xr[qq].x = in[b * 262144 + (qq * 4 + 0) * 4096 + rem];
                xr[qq].y = in[b * 262144 + (qq * 4 + 1) * 4096 + rem];
                xr[qq].z = in[b * 262144 + (qq * 4 + 2) * 4096 + rem];
                xr[qq].w = in[b * 262144 + (qq * 4 + 3) * 4096 + rem];
            }
        }
        double bv = 1e300;
        int    bi = 0;
        for (int j = 0; j < 16; ++j) {
            int c = (j << 6) + lane;
            const float4* er = (const float4*)(embed + (c << 6));
            double acc = 0.0;
#pragma unroll
            for (int qq = 0; qq < 16; ++qq) {
                float4 ev = er[qq];
                double d0 = (double)xr[qq].x - (double)ev.x;
                double d1 = (double)xr[qq].y - (double)ev.y;
                double d2 = (double)xr[qq].z - (double)ev.z;
                double d3 = (double)xr[qq].w - (double)ev.w;
                acc += d0 * d0 + d1 * d1 + d2 * d2 + d3 * d3;
            }
            if (acc < bv) { bv = acc; bi = c; }
        }
#pragma unroll
        for (int off = 1; off < 64; off <<= 1) {
            double ov = __shfl_xor(bv, off, 64);
            int    oi = __shfl_xor(bi, off, 64);
            if (ov < bv || (ov == bv && oi < bi)) { bv = ov; bi = oi; }
        }
        int oldi = (int)out_idx[r];
        if (bi != oldi) {
            float xd = flat_x ? flat_x[((size_t)r << 6) + lane]
                              : in[b * 262144 + lane * 4096 + rem];
            float en_ = embed[(bi << 6) + lane];
            float eo_ = embed[(oldi << 6) + lane];
            out_quant[b * 262144 + lane * 4096 + rem] = en_;
            float dl = (en_ - xd) * (en_ - xd) - (eo_ - xd) * (eo_ - xd);
#pragma unroll
            for (int off = 1; off < 64; off <<= 1) dl += __shfl_xor(dl, off, 64);
            if (lane == 0) {
                out_idx[r] = (float)bi;
                atomicAdd(&scal[0], dl);
                atomicSub(&counts_i[oldi], 1);
                atomicAdd(&counts_i[bi], 1);
            }
        }
        if (lane == 0) wlist[e] = 0;   // restore dwacc zero
    }
}

// ---- tail (frozen from R6) ----
__global__ __launch_bounds__(256) void vq_scatter_kernel(
    const float* __restrict__ idxf,
    const int*   __restrict__ counts_i,
    int* __restrict__ cursor,
    int* __restrict__ keys)
{
    __shared__ int lstarts[KCODES];
    __shared__ int lh[KCODES];
    __shared__ int part[256];
    const int t   = threadIdx.x;
    const int blk = blockIdx.x;

    int4 c4 = *(const int4*)(counts_i + (t << 2));
    part[t] = c4.x + c4.y + c4.z + c4.w;
    {
        int tb = t << 2;
        lh[tb] = 0; lh[tb + 1] = 0; lh[tb + 2] = 0; lh[tb + 3] = 0;
    }
    __syncthreads();
    for (int off = 1; off < 256; off <<= 1) {
        int v   = part[t];
        int add = (t >= off) ? part[t - off] : 0;
        __syncthreads();
        part[t] = v + add;
        __syncthreads();
    }
    {
        int base = (t == 0) ? 0 : part[t - 1];
        int tb = t << 2;
        lstarts[tb]     = base;
        lstarts[tb + 1] = base + c4.x;
        lstarts[tb + 2] = base + c4.x + c4.y;
        lstarts[tb + 3] = base + c4.x + c4.y + c4.z;
    }
    __syncthreads();

    const int i0 = (blk << 9) + t;
    const int i1 = i0 + 256;
    int code0 = (int)idxf[i0];
    int rank0 = atomicAdd(&lh[code0], 1);
    int code1 = (int)idxf[i1];
    int rank1 = atomicAdd(&lh[code1], 1);
    __syncthreads();
    for (int k = t; k < KCODES; k += 256) {
        int cnt = lh[k];
        if (cnt) lh[k] = lstarts[k] + atomicAdd(&cursor[k], cnt);
    }
    __syncthreads();
    keys[lh[code0] + rank0] = (code0 << 17) | i0;
    keys[lh[code1] + rank1] = (code1 << 17) | i1;
}

__global__ __launch_bounds__(256) void vq_dw_kernel(
    const float* __restrict__ flat_x,
    const int*   __restrict__ keys,
    float* __restrict__ dwacc)
{
    const int t   = threadIdx.x;
    const int blk = blockIdx.x;
    const int wv  = t >> 6, d = t & 63;
    const int base = (blk << 9) + (wv << 7);

    int key   = keys[base];
    int c_cur = key >> 17;
    int r     = key & 0x1FFFF;
    float acc = 0.f;
#pragma unroll 4
    for (int m = 0; m < 128; ++m) {
        float x = flat_x[((size_t)r << 6) + d];
        int nkey = (m < 127) ? keys[base + m + 1] : -1;
        int c_n  = nkey >> 17;
        int r_n  = nkey & 0x1FFFF;
        acc += x;
        if (c_n != c_cur) {
            atomicAdd(&dwacc[(c_cur << 6) + d], acc);
            acc = 0.f;
            c_cur = c_n;
        }
        r = r_n;
    }
}

__global__ __launch_bounds__(256) void vq_dw_nchw_kernel(
    const float* __restrict__ in,
    const int*   __restrict__ keys,
    float* __restrict__ dwacc)
{
    const int t   = threadIdx.x;
    const int blk = blockIdx.x;
    const int wv  = t >> 6, d = t & 63;
    const int base = (blk << 9) + (wv << 7);

    int key   = keys[base];
    int c_cur = key >> 17;
    int r     = key & 0x1FFFF;
    float acc = 0.f;
    for (int m = 0; m < 128; ++m) {
        int b = r >> 12, rem = r & 4095;
        float x = in[b * 262144 + d * 4096 + rem];
        int nkey = (m < 127) ? keys[base + m + 1] : -1;
        int c_n  = nkey >> 17;
        int r_n  = nkey & 0x1FFFF;
        acc += x;
        if (c_n != c_cur) {
            atomicAdd(&dwacc[(c_cur << 6) + d], acc);
            acc = 0.f;
            c_cur = c_n;
        }
        r = r_n;
    }
}

__global__ __launch_bounds__(256) void vq_fin_a_kernel(
    const float* __restrict__ ema_cs,
    const int*   __restrict__ counts_i,
    float* __restrict__ scal,
    float* __restrict__ out)
{
    __shared__ float r1[256], r2[256];
    const int t = threadIdx.x;
    const int k = blockIdx.x * 256 + t;
    float* o_ncs = out + QELEMS + 2 + NTOT;

    float c   = (float)counts_i[k];
    float ncs = 0.99f * ema_cs[k] + 0.01f * c;
    o_ncs[k] = ncs;
    float p = c / (float)NTOT;
    r1[t] = ncs;
    r2[t] = p * logf(p + 1e-10f);
    __syncthreads();
    for (int s = 128; s > 0; s >>= 1) {
        if (t < s) { r1[t] += r1[t + s]; r2[t] += r2[t + s]; }
        __syncthreads();
    }
    if (t == 0) {
        atomicAdd(&scal[1], r1[0]);
        atomicAdd(&scal[2], r2[0]);
    }
}

__global__ __launch_bounds__(256) void vq_fin_b_kernel(
    const float* __restrict__ ema_cs,
    const float* __restrict__ ema_w,
    const int*   __restrict__ counts_i,
    const float* __restrict__ dwacc,
    const float* __restrict__ scal,
    float* __restrict__ out)
{
    const int t = threadIdx.x;
    float* o_loss  = out + QELEMS;
    float* o_perp  = out + QELEMS + 1;
    float* o_ncs   = out + QELEMS + 2 + NTOT;
    float* o_emaw  = o_ncs + KCODES;
    float* o_embed = o_emaw + KCODES * DIM;

    float n = scal[1];
    float denom = n + (float)KCODES * 1e-5f;
#pragma unroll
    for (int u = 0; u < 8; ++u) {
        int i = (blockIdx.x << 11) + (u << 8) + t;
        int k = i >> 6;
        float c   = (float)counts_i[k];
        float ncs = 0.99f * ema_cs[k] + 0.01f * c;
        float cs  = (ncs + 1e-5f) / denom * n;
        cs = fmaxf(cs, 1e-5f);
        float w = 0.99f * ema_w[i] + 0.01f * dwacc[i];
        o_emaw[i]  = w;
        o_embed[i] = w / cs;
    }
    if (blockIdx.x == 0 && t == 0) {
        o_loss[0] = 0.25f * scal[0] / (float)QELEMS;
        o_perp[0] = expf(-scal[2]);
    }
}

extern "C" void kernel_launch(void* const* d_in, const int* in_sizes, int n_in,
                              void* d_out, int out_size, void* d_ws, size_t ws_size,
                              hipStream_t stream) {
    const float* in     = (const float*)d_in[0];
    const float* embed  = (const float*)d_in[1];
    const float* ema_cs = (const float*)d_in[2];
    const float* ema_w  = (const float*)d_in[3];
    float* out = (float*)d_out;
    float* ws  = (float*)d_ws;

    int*   counts_i = (int*)ws;              // 1024
    float* scal     = ws + 1024;             // 3 + wcount at 1027
    int*   wcount   = (int*)ws + 1027;
    int*   cursor   = (int*)ws + 1028;       // 1024
    float* dwacc    = ws + 2052;             // 65536 (worklist alias)
    int*   wlist    = (int*)ws + 2052;
    float* enorm    = ws + 67588;            // 1024
    _Float16* epk   = (_Float16*)(ws + 68612);   // argmin phase
    int*   keys     = (int*)ws + 68612;      // tail phase, aliases epk
    const bool use_flat = ws_size >= WS_NEED_FLAT;
    float* flat_x   = use_flat ? (ws + WS_FLAT_OFF) : (float*)0;
    float* o_idx    = out + QELEMS + 2;

    hipMemsetAsync(d_ws, 0, (size_t)WS_ZERO_FLOATS * sizeof(float), stream);
    vq_enorm_kernel<<<4, 256, 0, stream>>>(embed, enorm);
    vq_epack_kernel<<<16, 256, 0, stream>>>(embed, epk);
    vq_argmin_mfma<<<1024, 256, 0, stream>>>(in, embed, enorm, epk, out, o_idx,
                                             counts_i, scal, flat_x, wlist, wcount);
    vq_refine_kernel<<<64, 256, 0, stream>>>(embed, in, flat_x, o_idx, out,
                                             counts_i, scal, wlist, wcount);
    vq_scatter_kernel<<<256, 256, 0, stream>>>(o_idx, counts_i, cursor, keys);
    if (use_flat)
        vq_dw_kernel<<<256, 256, 0, stream>>>(flat_x, keys, dwacc);
    else
        vq_dw_nchw_kernel<<<256, 256, 0, stream>>>(in, keys, dwacc);
    vq_fin_a_kernel<<<4, 256, 0, stream>>>(ema_cs, counts_i, scal, out);
    vq_fin_b_kernel<<<32, 256, 0, stream>>>(ema_cs, ema_w, counts_i, dwacc, scal, out);
}

// Round 9
// 318.711 us; speedup vs baseline: 1.3628x; 1.3628x over previous
//
#include <hip/hip_runtime.h>
#include <math.h>

#define KCODES 1024
#define DIM 64
#define NTOT 131072          // 32*64*64 rows
#define QELEMS 8388608       // 32*64*64*64
#define TAU 1e-3f            // contested-margin threshold (>> fp16-split error bound)
#define WCAP 65536           // worklist capacity (aliases dwacc region)

typedef _Float16 half8 __attribute__((ext_vector_type(8)));
typedef float floatx4 __attribute__((ext_vector_type(4)));

// ws layout (4B units):
//   0      counts_i [1024] int     (zeroed)
//   1024   scal [3]: sumsq,nsum,ent; [1027] wcount int (zeroed)
//   1028   cursor [1024] int       (zeroed)
//   2052   dwacc [65536] float     (zeroed; doubles as refine worklist, re-zeroed)
//   67588  enorm [1024] float
//   68612  epk [65536 floats = 131072 halves]   (argmin phase)
//   68612  keys [131072] int                    (tail phase, aliases epk)
//   199684 flat_x [8388608] float  (optional)
#define WS_ZERO_FLOATS 67588
#define WS_FLAT_OFF 199684
#define WS_NEED_FLAT ((size_t)(WS_FLAT_OFF + QELEMS) * 4)

__global__ __launch_bounds__(256) void vq_enorm_kernel(const float* __restrict__ embed,
                                                       float* __restrict__ enorm) {
    int k = blockIdx.x * 256 + threadIdx.x;
    if (k < KCODES) {
        const float4* e4 = (const float4*)(embed + (k << 6));
        float s = 0.f;
#pragma unroll
        for (int j = 0; j < 16; ++j) {
            float4 v = e4[j];
            s += v.x * v.x + v.y * v.y + v.z * v.z + v.w * v.w;
        }
        enorm[k] = s;
    }
}

// Pack embed into MFMA A-fragment layout, fp16 split, 4 kc chunks (no dup):
// kc0=eh d[q*8+j], kc1=eh d[32+q*8+j], kc2=el d[q*8+j], kc3=el d[32+q*8+j].
// epk8[ctg*256 + kc*64 + lane]; A[m=lane&15][k=(lane>>4)*8+j] per 16-code tile ctg.
__global__ __launch_bounds__(256) void vq_epack_kernel(const float* __restrict__ embed,
                                                       _Float16* __restrict__ epk) {
    int tg   = blockIdx.x * 256 + threadIdx.x;   // 0..4095
    int ctg  = tg >> 6;
    int lane = tg & 63;
    int c    = ctg * 16 + (lane & 15);
    int q    = lane >> 4;
    const float* er = embed + c * 64;
    float4 f0 = *(const float4*)(er + q * 8);
    float4 f1 = *(const float4*)(er + q * 8 + 4);
    float4 g0 = *(const float4*)(er + 32 + q * 8);
    float4 g1 = *(const float4*)(er + 32 + q * 8 + 4);
    float va[8] = {f0.x, f0.y, f0.z, f0.w, f1.x, f1.y, f1.z, f1.w};
    float vb[8] = {g0.x, g0.y, g0.z, g0.w, g1.x, g1.y, g1.z, g1.w};
    half8 h0, h1, l0, l1;
#pragma unroll
    for (int j = 0; j < 8; ++j) {
        _Float16 ah = (_Float16)va[j];
        _Float16 bh = (_Float16)vb[j];
        h0[j] = ah;
        h1[j] = bh;
        l0[j] = (_Float16)(va[j] - (float)ah);
        l1[j] = (_Float16)(vb[j] - (float)bh);
    }
    half8* o = (half8*)epk;
    int base = ctg * 256 + lane;
    o[base]       = h0;
    o[base + 64]  = h1;
    o[base + 128] = l0;
    o[base + 192] = l1;
}

// MFMA argmin, pixel-resident: 256 blocks x 512 threads; wave owns 64 pixels
// (B-frags in VGPRs); 64 code tiles stream through L1/L2 (4 KB each, shared
// by all 8 waves). No barriers in the K-loop; epk HBM traffic ~= 256 KB total.
__global__ __launch_bounds__(512, 2) void vq_argmin_mfma(
    const float* __restrict__ in,        // [32][64][64][64] NCHW
    const float* __restrict__ embed,
    const float* __restrict__ enorm,
    const _Float16* __restrict__ epk,
    float* __restrict__ out_quant,
    float* __restrict__ out_idx,
    int*   __restrict__ counts_i,
    float* __restrict__ sumsq,
    float* __restrict__ flat_x,          // or nullptr
    int*   __restrict__ wlist,
    int*   __restrict__ wcount)
{
    __shared__ float en_s[KCODES];       // 4 KB
    __shared__ int   hist[KCODES];       // 4 KB
    __shared__ int   widx[512];          // 2 KB
    __shared__ float wv1[512];           // 2 KB
    __shared__ float rsum[512];          // 2 KB

    const int t    = threadIdx.x;
    const int blk  = blockIdx.x;         // 0..255 ; block = rows [blk*512, +512)
    const int lane = t & 63;
    const int w    = t >> 6;
    const int q    = lane >> 4;
    const int n    = lane & 15;

    for (int i = t; i < KCODES; i += 512) { en_s[i] = enorm[i]; hist[i] = 0; }

    // phase 1: flat_x dump + xnorm (thread = pixel; coalesced across lanes)
    const int row0 = (blk << 9) + t;
    const int b0 = row0 >> 12, rem0 = row0 & 4095;
    float xnorm = 0.f;
    {
        const float* pb = in + b0 * 262144 + rem0;
        float4* dst = flat_x ? (float4*)(flat_x + ((size_t)row0 << 6)) : (float4*)0;
#pragma unroll
        for (int d4 = 0; d4 < 16; ++d4) {
            float4 v;
            v.x = pb[(d4 * 4 + 0) * 4096];
            v.y = pb[(d4 * 4 + 1) * 4096];
            v.z = pb[(d4 * 4 + 2) * 4096];
            v.w = pb[(d4 * 4 + 3) * 4096];
            xnorm += v.x * v.x + v.y * v.y + v.z * v.z + v.w * v.w;
            if (dst) dst[d4] = v;
        }
    }
    __syncthreads();   // en_s / hist ready

    // phase 2: B-frags in registers (L2-hot re-read of in, frag-major)
    half8 bf0[4], bf1[4], bf2[4], bf3[4];
#pragma unroll
    for (int pt = 0; pt < 4; ++pt) {
        int row = (blk << 9) + (w << 6) + (pt << 4) + n;
        int b = row >> 12, rem = row & 4095;
        const float* pb = in + b * 262144 + rem;
#pragma unroll
        for (int j = 0; j < 8; ++j) {
            float xlo = pb[(q * 8 + j) * 4096];
            float xhi = pb[(q * 8 + j + 32) * 4096];
            _Float16 hl = (_Float16)xlo;
            _Float16 hh = (_Float16)xhi;
            bf0[pt][j] = hl;
            bf2[pt][j] = (_Float16)(xlo - (float)hl);
            bf1[pt][j] = hh;
            bf3[pt][j] = (_Float16)(xhi - (float)hh);
        }
    }

    // phase 3: stream 64 code tiles; 3-term fp16 split via register reuse
    float v1[4], v2[4];
    int   i1[4];
#pragma unroll
    for (int pt = 0; pt < 4; ++pt) { v1[pt] = 3.4e38f; v2[pt] = 3.4e38f; i1[pt] = 0; }

    const half8* epk8 = (const half8*)epk;
    for (int ctg = 0; ctg < 64; ++ctg) {
        half8 a0 = epk8[ctg * 256 + lane];
        half8 a1 = epk8[ctg * 256 + 64 + lane];
        half8 a2 = epk8[ctg * 256 + 128 + lane];
        half8 a3 = epk8[ctg * 256 + 192 + lane];
        floatx4 enf = *(const floatx4*)&en_s[ctg * 16 + q * 4];
        const int c0 = ctg * 16 + q * 4;
#pragma unroll
        for (int pt = 0; pt < 4; ++pt) {
            floatx4 acc = {0.f, 0.f, 0.f, 0.f};
            acc = __builtin_amdgcn_mfma_f32_16x16x32_f16(a0, bf0[pt], acc, 0, 0, 0);
            acc = __builtin_amdgcn_mfma_f32_16x16x32_f16(a1, bf1[pt], acc, 0, 0, 0);
            acc = __builtin_amdgcn_mfma_f32_16x16x32_f16(a2, bf0[pt], acc, 0, 0, 0);
            acc = __builtin_amdgcn_mfma_f32_16x16x32_f16(a3, bf1[pt], acc, 0, 0, 0);
            acc = __builtin_amdgcn_mfma_f32_16x16x32_f16(a0, bf2[pt], acc, 0, 0, 0);
            acc = __builtin_amdgcn_mfma_f32_16x16x32_f16(a1, bf3[pt], acc, 0, 0, 0);
#pragma unroll
            for (int r = 0; r < 4; ++r) {
                float dv = enf[r] - 2.0f * acc[r];
                if (dv < v1[pt]) { v2[pt] = v1[pt]; v1[pt] = dv; i1[pt] = c0 + r; }
                else if (dv < v2[pt]) v2[pt] = dv;
            }
        }
    }

    // phase 4: per-wave quad merge (pixels are wave-exclusive -> no LDS merge)
#pragma unroll
    for (int pt = 0; pt < 4; ++pt) {
        float a1v = v1[pt], a2v = v2[pt];
        int   ai  = i1[pt];
#pragma unroll
        for (int off = 16; off <= 32; off <<= 1) {
            float o1 = __shfl_xor(a1v, off, 64);
            int   oi = __shfl_xor(ai, off, 64);
            float o2 = __shfl_xor(a2v, off, 64);
            if (o1 < a1v || (o1 == a1v && oi < ai)) {
                a2v = fminf(a1v, o2); a1v = o1; ai = oi;
            } else {
                a2v = fminf(a2v, o1);
            }
        }
        if (lane < 16) {
            int pl  = (w << 6) + (pt << 4) + lane;
            int row = (blk << 9) + pl;
            widx[pl] = ai;
            wv1[pl]  = a1v;
            out_idx[row] = (float)ai;
            atomicAdd(&hist[ai], 1);
            if (a2v - a1v < TAU) {
                int pos = atomicAdd(wcount, 1);
                if (pos < WCAP) wlist[pos] = row;
            }
        }
    }
    __syncthreads();

    // phase 5: hist flush + quant write + sumsq (v1 + |x|^2)
    for (int i = t; i < KCODES; i += 512) {
        int v = hist[i];
        if (v) atomicAdd(&counts_i[i], v);
    }
    {
        int k = widx[t];
        const float4* eq = (const float4*)(embed + (k << 6));
        float* ob = out_quant + b0 * 262144 + rem0;
#pragma unroll
        for (int d4 = 0; d4 < 16; ++d4) {
            float4 e4v = eq[d4];
            ob[(d4 * 4 + 0) * 4096] = e4v.x;
            ob[(d4 * 4 + 1) * 4096] = e4v.y;
            ob[(d4 * 4 + 2) * 4096] = e4v.z;
            ob[(d4 * 4 + 3) * 4096] = e4v.w;
        }
        rsum[t] = wv1[t] + xnorm;
    }
    __syncthreads();
    for (int s = 256; s > 0; s >>= 1) {
        if (t < s) rsum[t] += rsum[t + s];
        __syncthreads();
    }
    if (t == 0) atomicAdd(sumsq, rsum[0]);
}

// Exact double-precision refine of contested pixels (frozen from R8).
__global__ __launch_bounds__(256) void vq_refine_kernel(
    const float* __restrict__ embed,
    const float* __restrict__ in,
    const float* __restrict__ flat_x,    // may be null
    float* __restrict__ out_idx,
    float* __restrict__ out_quant,
    int*   __restrict__ counts_i,
    float* __restrict__ scal,            // [0]=sumsq
    int*   __restrict__ wlist,
    const int* __restrict__ wcount)
{
    const int lane = threadIdx.x & 63;
    const int gw   = (blockIdx.x << 2) + (threadIdx.x >> 6);
    const int nw   = gridDim.x << 2;
    int count = *wcount;
    if (count > WCAP) count = WCAP;

    for (int e = gw; e < count; e += nw) {
        int r = wlist[e];
        int b = r >> 12, rem = r & 4095;
        float4 xr[16];
        if (flat_x) {
            const float4* xs4 = (const float4*)(flat_x + ((size_t)r << 6));
#pragma unroll
            for (int qq = 0; qq < 16; ++qq) xr[qq] = xs4[qq];
        } else {
#pragma unroll
            for (int qq = 0; qq < 16; ++qq) {
                xr[qq].x = in[b * 262144 + (qq * 4 + 0) * 4096 + rem];
                xr[qq].y = in[b * 262144 + (qq * 4 + 1) * 4096 + rem];
                xr[qq].z = in[b * 262144 + (qq * 4 + 2) * 4096 + rem];
                xr[qq].w = in[b * 262144 + (qq * 4 + 3) * 4096 + rem];
            }
        }
        double bv = 1e300;
        int    bi = 0;
        for (int j = 0; j < 16; ++j) {
            int c = (j << 6) + lane;
            const float4* er = (const float4*)(embed + (c << 6));
            double acc = 0.0;
#pragma unroll
            for (int qq = 0; qq < 16; ++qq) {
                float4 ev = er[qq];
                double d0 = (double)xr[qq].x - (double)ev.x;
                double d1 = (double)xr[qq].y - (double)ev.y;
                double d2 = (double)xr[qq].z - (double)ev.z;
                double d3 = (double)xr[qq].w - (double)ev.w;
                acc += d0 * d0 + d1 * d1 + d2 * d2 + d3 * d3;
            }
            if (acc < bv) { bv = acc; bi = c; }
        }
#pragma unroll
        for (int off = 1; off < 64; off <<= 1) {
            double ov = __shfl_xor(bv, off, 64);
            int    oi = __shfl_xor(bi, off, 64);
            if (ov < bv || (ov == bv && oi < bi)) { bv = ov; bi = oi; }
        }
        int oldi = (int)out_idx[r];
        if (bi != oldi) {
            float xd = flat_x ? flat_x[((size_t)r << 6) + lane]
                              : in[b * 262144 + lane * 4096 + rem];
            float en_ = embed[(bi << 6) + lane];
            float eo_ = embed[(oldi << 6) + lane];
            out_quant[b * 262144 + lane * 4096 + rem] = en_;
            float dl = (en_ - xd) * (en_ - xd) - (eo_ - xd) * (eo_ - xd);
#pragma unroll
            for (int off = 1; off < 64; off <<= 1) dl += __shfl_xor(dl, off, 64);
            if (lane == 0) {
                out_idx[r] = (float)bi;
                atomicAdd(&scal[0], dl);
                atomicSub(&counts_i[oldi], 1);
                atomicAdd(&counts_i[bi], 1);
            }
        }
        if (lane == 0) wlist[e] = 0;   // restore dwacc zero
    }
}

// ---- tail (frozen from R6) ----
__global__ __launch_bounds__(256) void vq_scatter_kernel(
    const float* __restrict__ idxf,
    const int*   __restrict__ counts_i,
    int* __restrict__ cursor,
    int* __restrict__ keys)
{
    __shared__ int lstarts[KCODES];
    __shared__ int lh[KCODES];
    __shared__ int part[256];
    const int t   = threadIdx.x;
    const int blk = blockIdx.x;

    int4 c4 = *(const int4*)(counts_i + (t << 2));
    part[t] = c4.x + c4.y + c4.z + c4.w;
    {
        int tb = t << 2;
        lh[tb] = 0; lh[tb + 1] = 0; lh[tb + 2] = 0; lh[tb + 3] = 0;
    }
    __syncthreads();
    for (int off = 1; off < 256; off <<= 1) {
        int v   = part[t];
        int add = (t >= off) ? part[t - off] : 0;
        __syncthreads();
        part[t] = v + add;
        __syncthreads();
    }
    {
        int base = (t == 0) ? 0 : part[t - 1];
        int tb = t << 2;
        lstarts[tb]     = base;
        lstarts[tb + 1] = base + c4.x;
        lstarts[tb + 2] = base + c4.x + c4.y;
        lstarts[tb + 3] = base + c4.x + c4.y + c4.z;
    }
    __syncthreads();

    const int i0 = (blk << 9) + t;
    const int i1 = i0 + 256;
    int code0 = (int)idxf[i0];
    int rank0 = atomicAdd(&lh[code0], 1);
    int code1 = (int)idxf[i1];
    int rank1 = atomicAdd(&lh[code1], 1);
    __syncthreads();
    for (int k = t; k < KCODES; k += 256) {
        int cnt = lh[k];
        if (cnt) lh[k] = lstarts[k] + atomicAdd(&cursor[k], cnt);
    }
    __syncthreads();
    keys[lh[code0] + rank0] = (code0 << 17) | i0;
    keys[lh[code1] + rank1] = (code1 << 17) | i1;
}

__global__ __launch_bounds__(256) void vq_dw_kernel(
    const float* __restrict__ flat_x,
    const int*   __restrict__ keys,
    float* __restrict__ dwacc)
{
    const int t   = threadIdx.x;
    const int blk = blockIdx.x;
    const int wv  = t >> 6, d = t & 63;
    const int base = (blk << 9) + (wv << 7);

    int key   = keys[base];
    int c_cur = key >> 17;
    int r     = key & 0x1FFFF;
    float acc = 0.f;
#pragma unroll 4
    for (int m = 0; m < 128; ++m) {
        float x = flat_x[((size_t)r << 6) + d];
        int nkey = (m < 127) ? keys[base + m + 1] : -1;
        int c_n  = nkey >> 17;
        int r_n  = nkey & 0x1FFFF;
        acc += x;
        if (c_n != c_cur) {
            atomicAdd(&dwacc[(c_cur << 6) + d], acc);
            acc = 0.f;
            c_cur = c_n;
        }
        r = r_n;
    }
}

__global__ __launch_bounds__(256) void vq_dw_nchw_kernel(
    const float* __restrict__ in,
    const int*   __restrict__ keys,
    float* __restrict__ dwacc)
{
    const int t   = threadIdx.x;
    const int blk = blockIdx.x;
    const int wv  = t >> 6, d = t & 63;
    const int base = (blk << 9) + (wv << 7);

    int key   = keys[base];
    int c_cur = key >> 17;
    int r     = key & 0x1FFFF;
    float acc = 0.f;
    for (int m = 0; m < 128; ++m) {
        int b = r >> 12, rem = r & 4095;
        float x = in[b * 262144 + d * 4096 + rem];
        int nkey = (m < 127) ? keys[base + m + 1] : -1;
        int c_n  = nkey >> 17;
        int r_n  = nkey & 0x1FFFF;
        acc += x;
        if (c_n != c_cur) {
            atomicAdd(&dwacc[(c_cur << 6) + d], acc);
            acc = 0.f;
            c_cur = c_n;
        }
        r = r_n;
    }
}

__global__ __launch_bounds__(256) void vq_fin_a_kernel(
    const float* __restrict__ ema_cs,
    const int*   __restrict__ counts_i,
    float* __restrict__ scal,
    float* __restrict__ out)
{
    __shared__ float r1[256], r2[256];
    const int t = threadIdx.x;
    const int k = blockIdx.x * 256 + t;
    float* o_ncs = out + QELEMS + 2 + NTOT;

    float c   = (float)counts_i[k];
    float ncs = 0.99f * ema_cs[k] + 0.01f * c;
    o_ncs[k] = ncs;
    float p = c / (float)NTOT;
    r1[t] = ncs;
    r2[t] = p * logf(p + 1e-10f);
    __syncthreads();
    for (int s = 128; s > 0; s >>= 1) {
        if (t < s) { r1[t] += r1[t + s]; r2[t] += r2[t + s]; }
        __syncthreads();
    }
    if (t == 0) {
        atomicAdd(&scal[1], r1[0]);
        atomicAdd(&scal[2], r2[0]);
    }
}

__global__ __launch_bounds__(256) void vq_fin_b_kernel(
    const float* __restrict__ ema_cs,
    const float* __restrict__ ema_w,
    const int*   __restrict__ counts_i,
    const float* __restrict__ dwacc,
    const float* __restrict__ scal,
    float* __restrict__ out)
{
    const int t = threadIdx.x;
    float* o_loss  = out + QELEMS;
    float* o_perp  = out + QELEMS + 1;
    float* o_ncs   = out + QELEMS + 2 + NTOT;
    float* o_emaw  = o_ncs + KCODES;
    float* o_embed = o_emaw + KCODES * DIM;

    float n = scal[1];
    float denom = n + (float)KCODES * 1e-5f;
#pragma unroll
    for (int u = 0; u < 8; ++u) {
        int i = (blockIdx.x << 11) + (u << 8) + t;
        int k = i >> 6;
        float c   = (float)counts_i[k];
        float ncs = 0.99f * ema_cs[k] + 0.01f * c;
        float cs  = (ncs + 1e-5f) / denom * n;
        cs = fmaxf(cs, 1e-5f);
        float w = 0.99f * ema_w[i] + 0.01f * dwacc[i];
        o_emaw[i]  = w;
        o_embed[i] = w / cs;
    }
    if (blockIdx.x == 0 && t == 0) {
        o_loss[0] = 0.25f * scal[0] / (float)QELEMS;
        o_perp[0] = expf(-scal[2]);
    }
}

extern "C" void kernel_launch(void* const* d_in, const int* in_sizes, int n_in,
                              void* d_out, int out_size, void* d_ws, size_t ws_size,
                              hipStream_t stream) {
    const float* in     = (const float*)d_in[0];
    const float* embed  = (const float*)d_in[1];
    const float* ema_cs = (const float*)d_in[2];
    const float* ema_w  = (const float*)d_in[3];
    float* out = (float*)d_out;
    float* ws  = (float*)d_ws;

    int*   counts_i = (int*)ws;              // 1024
    float* scal     = ws + 1024;             // 3 + wcount at 1027
    int*   wcount   = (int*)ws + 1027;
    int*   cursor   = (int*)ws + 1028;       // 1024
    float* dwacc    = ws + 2052;             // 65536 (worklist alias)
    int*   wlist    = (int*)ws + 2052;
    float* enorm    = ws + 67588;            // 1024
    _Float16* epk   = (_Float16*)(ws + 68612);   // 131072 halves (argmin phase)
    int*   keys     = (int*)ws + 68612;      // tail phase, aliases epk
    const bool use_flat = ws_size >= WS_NEED_FLAT;
    float* flat_x   = use_flat ? (ws + WS_FLAT_OFF) : (float*)0;
    float* o_idx    = out + QELEMS + 2;

    hipMemsetAsync(d_ws, 0, (size_t)WS_ZERO_FLOATS * sizeof(float), stream);
    vq_enorm_kernel<<<4, 256, 0, stream>>>(embed, enorm);
    vq_epack_kernel<<<16, 256, 0, stream>>>(embed, epk);
    vq_argmin_mfma<<<256, 512, 0, stream>>>(in, embed, enorm, epk, out, o_idx,
                                            counts_i, scal, flat_x, wlist, wcount);
    vq_refine_kernel<<<64, 256, 0, stream>>>(embed, in, flat_x, o_idx, out,
                                             counts_i, scal, wlist, wcount);
    vq_scatter_kernel<<<256, 256, 0, stream>>>(o_idx, counts_i, cursor, keys);
    if (use_flat)
        vq_dw_kernel<<<256, 256, 0, stream>>>(flat_x, keys, dwacc);
    else
        vq_dw_nchw_kernel<<<256, 256, 0, stream>>>(in, keys, dwacc);
    vq_fin_a_kernel<<<4, 256, 0, stream>>>(ema_cs, counts_i, scal, out);
    vq_fin_b_kernel<<<32, 256, 0, stream>>>(ema_cs, ema_w, counts_i, dwacc, scal, out);
}